// Round 11
// baseline (73.097 us; speedup 1.0000x reference)
//
#include <hip/hip_runtime.h>

typedef __attribute__((ext_vector_type(4))) int   i32x4;
typedef __attribute__((ext_vector_type(4))) float f32x4;

#define TF    32768   // T*F
#define TF4   8192    // TF/4
#define NS    2048    // N samples
#define NG    32      // k34 sample-groups
#define WCUT  1e-9f   // weight cutoff: skipped mass <= 2048*1e-9 ~ 2e-6

// mask accessor: isI32 ? int32[] : byte-bool[]
__device__ __forceinline__ i32x4 mload4(const void* mask, int isI32, int idx4) {
  if (isI32) return ((const i32x4*)mask)[idx4];
  unsigned int w = ((const unsigned int*)mask)[idx4];
  i32x4 r;
  r[0] = (int)(w & 0xFFu);
  r[1] = (int)((w >> 8) & 0xFFu);
  r[2] = (int)((w >> 16) & 0xFFu);
  r[3] = (int)((w >> 24) & 0xFFu);
  return r;
}

__device__ __forceinline__ double ac_fn(int t) {
  const double s = 0.008;
  double c = cos(((double)t / 1000.0 + s) / (1.0 + s) * 1.5707963267948966);
  return c * c;
}
__device__ __forceinline__ double alpha_fn(int t) {
  double beta = 1.0 - ac_fn(t + 1) / ac_fn(t);
  beta = beta < 0.0 ? 0.0 : (beta > 0.999 ? 0.999 : beta);
  return 1.0 - beta;
}

// ---------- K1: fused probe + schedule + tables (grid 32) ----------
//   missing:  sc=sig, xq=x, pq=pred          -> d = clip(e*sig+x) - pred
//   observed: sc=0,   xq=0, pq=(obs-pred)    -> v=0, d^2 = (obs-pred)^2
__launch_bounds__(256)
__global__ void k1_fused(const int* __restrict__ ip,
                         const unsigned int* __restrict__ maskw,
                         const float* __restrict__ timep,
                         const float* __restrict__ dega,
                         const float* __restrict__ degb,
                         const float* __restrict__ xbar,
                         const float* __restrict__ obs,
                         const void* __restrict__ mask,
                         float* __restrict__ wsc,
                         float* __restrict__ sc, float* __restrict__ xq,
                         float* __restrict__ pq) {
  const int tid = threadIdx.x;
  __shared__ int badsh;
  __shared__ double prod[256];
  __shared__ float ssig;
  __shared__ int sIsI32;
  if (tid == 0) badsh = 0;
  __syncthreads();
  int bad = 0;
  for (int k = tid; k < TF4; k += 256)
    if (maskw[k] > 1u) bad = 1;           // int32 0/1 mask never triggers
  if (bad) atomicOr(&badsh, 1);

  const int i = ip[0];
  double p = 1.0;
  for (int t = tid; t < i; t += 256) p *= alpha_fn(t);
  prod[tid] = p;
  __syncthreads();
  for (int s = 128; s > 0; s >>= 1) {
    if (tid < s) prod[tid] *= prod[tid + s];
    __syncthreads();
  }
  if (tid == 0) {
    double acp_im1 = prod[0];
    double ai = alpha_fn(i);
    double acp_i = acp_im1 * ai;
    float sig = (float)sqrt(1.0 - acp_i);
    ssig = sig;
    sIsI32 = badsh ? 0 : 1;
    if (blockIdx.x == 0) {
      wsc[0] = sig;                 // sigma_i
      wsc[1] = (float)acp_i;        // abar_i
      wsc[2] = (float)ai;           // alpha_i
      wsc[3] = (float)acp_im1;      // abar_{i-1}
      ((int*)wsc)[8] = badsh ? 0 : 1;
    }
  }
  __syncthreads();
  const float sig = ssig;
  const int isI32 = sIsI32;

  const int pos4 = blockIdx.x * 256 + tid;   // 0..8191
  const int t  = pos4 >> 4;
  const int f0 = (pos4 << 2) & 63;
  const float tv = timep[t];
  f32x4 da = *(const f32x4*)(dega + f0);
  f32x4 db = *(const f32x4*)(degb + f0);
  f32x4 x  = ((const f32x4*)xbar)[pos4];
  f32x4 o  = ((const f32x4*)obs)[pos4];
  i32x4 m  = mload4(mask, isI32, pos4);

  f32x4 scv, xqv, pqv;
  #pragma unroll
  for (int c = 0; c < 4; ++c) {
    const float pr = fmaf(db[c], tv, da[c]);
    const bool mm = m[c] != 0;
    scv[c] = mm ? 0.f : sig;
    xqv[c] = mm ? 0.f : x[c];
    pqv[c] = mm ? (o[c] - pr) : pr;
  }
  ((f32x4*)sc)[pos4] = scv;
  ((f32x4*)xq)[pos4] = xqv;
  ((f32x4*)pq)[pos4] = pqv;
}

// ---------- K2: per-sample score partials (4 samples x 4 k-quarters) ----------
// R6 structure; eps loads NON-TEMPORAL (no L3 allocate) to avoid MALL thrash
// on the 268MB one-shot stream.
__launch_bounds__(256)
__global__ void k2_scores(const float* __restrict__ eps,
                          const float* __restrict__ sc,
                          const float* __restrict__ xq,
                          const float* __restrict__ pq,
                          double* __restrict__ pscore) {
  const int tid = threadIdx.x;
  const int n0 = blockIdx.x * 4;
  const int kq = blockIdx.y;
  const int kbeg = kq * (TF4 / 4);           // 2048 positions per quarter
  const f32x4* e4 = (const f32x4*)eps;
  const f32x4* sc4 = (const f32x4*)sc;
  const f32x4* xq4 = (const f32x4*)xq;
  const f32x4* pq4 = (const f32x4*)pq;

  double acc[4] = {0.0, 0.0, 0.0, 0.0};
  #pragma unroll 2
  for (int k = kbeg + tid; k < kbeg + TF4 / 4; k += 512) {
    const int k1 = k + 256;
    f32x4 sv0 = sc4[k],  xv0 = xq4[k],  pv0 = pq4[k];
    f32x4 sv1 = sc4[k1], xv1 = xq4[k1], pv1 = pq4[k1];
    #pragma unroll
    for (int r = 0; r < 4; ++r) {
      const size_t row = (size_t)(n0 + r) * TF4;
      f32x4 e0 = __builtin_nontemporal_load(e4 + row + k);
      f32x4 e1 = __builtin_nontemporal_load(e4 + row + k1);
      float s = 0.f;
      #pragma unroll
      for (int c = 0; c < 4; ++c) {
        float v = fmaf(e0[c], sv0[c], xv0[c]);
        v = fminf(fmaxf(v, -1.f), 1.f);
        float d = v - pv0[c];
        s = fmaf(d, d, s);
      }
      #pragma unroll
      for (int c = 0; c < 4; ++c) {
        float v = fmaf(e1[c], sv1[c], xv1[c]);
        v = fminf(fmaxf(v, -1.f), 1.f);
        float d = v - pv1[c];
        s = fmaf(d, d, s);
      }
      acc[r] += (double)s;
    }
  }
  __shared__ double red[4 * 256];
  #pragma unroll
  for (int r = 0; r < 4; ++r) red[r * 256 + tid] = acc[r];
  __syncthreads();
  for (int s = 128; s > 0; s >>= 1) {
    if (tid < s) {
      #pragma unroll
      for (int r = 0; r < 4; ++r) red[r * 256 + tid] += red[r * 256 + tid + s];
    }
    __syncthreads();
  }
  if (tid < 4) pscore[kq * NS + n0 + tid] = red[tid * 256];
}

// ---------- K34: softmax+compaction (redundant/block, LDS) + weighted partial ----------
__launch_bounds__(256)
__global__ void k34_weighted(const double* __restrict__ pscore,
                             const float* __restrict__ eps,
                             const float* __restrict__ xbar,
                             const float* __restrict__ wsc,
                             float* __restrict__ partial) {
  const int tid = threadIdx.x;
  __shared__ double red[256];
  __shared__ int cnt[256];
  __shared__ int   ciL[NS];
  __shared__ float cwL[NS];

  float s[8];
  #pragma unroll
  for (int j = 0; j < 8; ++j) {
    int n = tid + 256 * j;
    double t = pscore[n] + pscore[NS + n] + pscore[2 * NS + n] + pscore[3 * NS + n];
    s[j] = -(float)(t * (1.0 / 32768.0));
  }
  double t = 0.0;
  #pragma unroll
  for (int j = 0; j < 8; ++j) t += (double)s[j];
  red[tid] = t; __syncthreads();
  for (int st = 128; st > 0; st >>= 1) { if (tid < st) red[tid] += red[tid + st]; __syncthreads(); }
  const float mean = (float)(red[0] * (1.0 / 2048.0));
  __syncthreads();
  double v = 0.0;
  #pragma unroll
  for (int j = 0; j < 8; ++j) { float d = s[j] - mean; v += (double)d * (double)d; }
  red[tid] = v; __syncthreads();
  for (int st = 128; st > 0; st >>= 1) { if (tid < st) red[tid] += red[tid + st]; __syncthreads(); }
  float stdv = (float)sqrt(red[0] / 2047.0);   // ddof=1
  stdv = fmaxf(stdv, 1e-4f);
  const float inv = 10.0f / stdv;              // /std /0.1
  float lp[8];
  double mx = -1e300;
  #pragma unroll
  for (int j = 0; j < 8; ++j) { lp[j] = (s[j] - mean) * inv; mx = fmax(mx, (double)lp[j]); }
  __syncthreads();
  red[tid] = mx; __syncthreads();
  for (int st = 128; st > 0; st >>= 1) { if (tid < st) red[tid] = fmax(red[tid], red[tid + st]); __syncthreads(); }
  const float M = (float)red[0];
  __syncthreads();
  float ev[8]; double es = 0.0;
  #pragma unroll
  for (int j = 0; j < 8; ++j) { ev[j] = expf(lp[j] - M); es += (double)ev[j]; }
  red[tid] = es; __syncthreads();
  for (int st = 128; st > 0; st >>= 1) { if (tid < st) red[tid] += red[tid + st]; __syncthreads(); }
  const float invS = (float)(1.0 / red[0]);

  float w[8]; int keep[8]; int c = 0;
  #pragma unroll
  for (int j = 0; j < 8; ++j) {
    w[j] = ev[j] * invS;
    keep[j] = w[j] > WCUT;
    c += keep[j];
  }
  cnt[tid] = c; __syncthreads();
  for (int off = 1; off < 256; off <<= 1) {
    int vv = (tid >= off) ? cnt[tid - off] : 0;
    __syncthreads();
    cnt[tid] += vv;
    __syncthreads();
  }
  int base = cnt[tid] - c;              // exclusive prefix
  #pragma unroll
  for (int j = 0; j < 8; ++j) {
    if (keep[j]) {
      ciL[base] = tid + 256 * j;
      cwL[base] = w[j];
      ++base;
    }
  }
  const int Nk = cnt[255];
  __syncthreads();

  const int pos4 = blockIdx.x * 256 + tid;   // 0..8191
  const int g = blockIdx.y;                  // 0..NG-1
  const float sig = wsc[0];
  const f32x4* e4 = (const f32x4*)eps;
  f32x4 xf = ((const f32x4*)xbar)[pos4];
  f32x4 acc = {0.f, 0.f, 0.f, 0.f};
  int j = g;
  for (; j + NG < Nk; j += 2 * NG) {
    const float w0 = cwL[j];
    const int   n0 = ciL[j];
    const float w1 = cwL[j + NG];
    const int   n1 = ciL[j + NG];
    f32x4 e0 = e4[(size_t)n0 * TF4 + pos4];
    f32x4 e1 = e4[(size_t)n1 * TF4 + pos4];
    #pragma unroll
    for (int c2 = 0; c2 < 4; ++c2) {
      float vv = fmaf(e0[c2], sig, xf[c2]);
      vv = fminf(fmaxf(vv, -1.f), 1.f);
      acc[c2] = fmaf(w0, vv, acc[c2]);
    }
    #pragma unroll
    for (int c2 = 0; c2 < 4; ++c2) {
      float vv = fmaf(e1[c2], sig, xf[c2]);
      vv = fminf(fmaxf(vv, -1.f), 1.f);
      acc[c2] = fmaf(w1, vv, acc[c2]);
    }
  }
  for (; j < Nk; j += NG) {
    const float ww = cwL[j];
    const int n = ciL[j];
    f32x4 e = e4[(size_t)n * TF4 + pos4];
    #pragma unroll
    for (int c2 = 0; c2 < 4; ++c2) {
      float vv = fmaf(e[c2], sig, xf[c2]);
      vv = fminf(fmaxf(vv, -1.f), 1.f);
      acc[c2] = fmaf(ww, vv, acc[c2]);
    }
  }
  ((f32x4*)partial)[(size_t)g * TF4 + pos4] = acc;
}

// ---------- K5: reduce partials + final combine -> f32 out ----------
__launch_bounds__(256)
__global__ void k5_final(const float* __restrict__ partial,
                         const float* __restrict__ xbar,
                         const float* __restrict__ obs,
                         const void* __restrict__ mask,
                         const float* __restrict__ wsc,
                         float* __restrict__ out) {
  const int pos4 = blockIdx.x * 256 + threadIdx.x;  // grid 32
  const f32x4* p4 = (const f32x4*)partial;
  f32x4 w = {0.f, 0.f, 0.f, 0.f};
  #pragma unroll 8
  for (int g = 0; g < NG; ++g) {
    f32x4 a = p4[(size_t)g * TF4 + pos4];
    #pragma unroll
    for (int c = 0; c < 4; ++c) w[c] += a[c];
  }
  const float abar = wsc[1];
  const float sa = sqrtf(abar);
  const float ra = 1.f / sqrtf(wsc[2]);
  const float rb = 1.f / sqrtf(wsc[3]);
  const int isI32 = ((const int*)wsc)[8];
  f32x4 xf = ((const f32x4*)xbar)[pos4];
  f32x4 ov = ((const f32x4*)obs)[pos4];
  i32x4 m = mload4(mask, isI32, pos4);
  f32x4 res;
  #pragma unroll
  for (int c = 0; c < 4; ++c) {
    const float Yi = sa * xf[c];
    const float scv = (-Yi + sa * w[c]) / (1.f - abar);
    const float xim1 = (Yi + (1.f - abar) * scv) * ra;
    res[c] = m[c] ? ov[c] : (xim1 * rb);
  }
  ((f32x4*)out)[pos4] = res;
}

extern "C" void kernel_launch(void* const* d_in, const int* in_sizes, int n_in,
                              void* d_out, int out_size, void* d_ws, size_t ws_size,
                              hipStream_t stream) {
  const float* Xbar  = (const float*)d_in[0];
  const float* obs   = (const float*)d_in[1];
  const float* timep = (const float*)d_in[2];
  const void*  mask  = d_in[3];
  const float* eps   = (const float*)d_in[4];
  const float* dega  = (const float*)d_in[5];
  const float* degb  = (const float*)d_in[6];
  const int*   ip    = (const int*)d_in[7];

  float* ws = (float*)d_ws;
  float*  wsc     = ws;                          // 16 floats (+flags)
  float*  sc      = ws + 16;                     // 32768
  float*  xq      = sc + TF;                     // 32768
  float*  pq      = xq + TF;                     // 32768
  double* pscore  = (double*)(pq + TF);          // 4*2048 doubles (8B-aligned)
  float*  partial = (float*)(pscore + 4 * NS);   // NG*32768 floats (4 MiB)

  hipLaunchKernelGGL(k1_fused,   dim3(32),       dim3(256), 0, stream,
                     ip, (const unsigned int*)mask, timep, dega, degb,
                     Xbar, obs, mask, wsc, sc, xq, pq);
  hipLaunchKernelGGL(k2_scores,  dim3(NS/4, 4),  dim3(256), 0, stream,
                     eps, sc, xq, pq, pscore);
  hipLaunchKernelGGL(k34_weighted, dim3(32, NG), dim3(256), 0, stream,
                     pscore, eps, Xbar, wsc, partial);
  hipLaunchKernelGGL(k5_final,     dim3(32),     dim3(256), 0, stream,
                     partial, Xbar, obs, mask, wsc, (float*)d_out);
}

// Round 12
// 70.814 us; speedup vs baseline: 1.0322x; 1.0322x over previous
//
#include <hip/hip_runtime.h>

typedef __attribute__((ext_vector_type(4))) int   i32x4;
typedef __attribute__((ext_vector_type(4))) float f32x4;

#define TF    32768   // T*F
#define TF4   8192    // TF/4
#define NS    2048    // N samples
#define NG    32      // k34 sample-groups
#define WCUT  1e-9f   // weight cutoff: skipped mass <= 2048*1e-9 ~ 2e-6

// mask accessor: isI32 ? int32[] : byte-bool[]
__device__ __forceinline__ i32x4 mload4(const void* mask, int isI32, int idx4) {
  if (isI32) return ((const i32x4*)mask)[idx4];
  unsigned int w = ((const unsigned int*)mask)[idx4];
  i32x4 r;
  r[0] = (int)(w & 0xFFu);
  r[1] = (int)((w >> 8) & 0xFFu);
  r[2] = (int)((w >> 16) & 0xFFu);
  r[3] = (int)((w >> 24) & 0xFFu);
  return r;
}

__device__ __forceinline__ double ac_fn(int t) {
  const double s = 0.008;
  double c = cos(((double)t / 1000.0 + s) / (1.0 + s) * 1.5707963267948966);
  return c * c;
}
__device__ __forceinline__ double alpha_fn(int t) {
  double beta = 1.0 - ac_fn(t + 1) / ac_fn(t);
  beta = beta < 0.0 ? 0.0 : (beta > 0.999 ? 0.999 : beta);
  return 1.0 - beta;
}

// ---------- K1: fused probe + schedule + tables (grid 32) ----------
// Tables: xq,pq (f32x4/pos4) + bm (1 byte/pos4, bit c = observed).
//   missing:  sv=sig, xq=x, pq=pred          -> d = clip(e*sig+x) - pred
//   observed: sv=0,   xq=0, pq=(obs-pred)    -> v=0, d^2 = (obs-pred)^2
__launch_bounds__(256)
__global__ void k1_fused(const int* __restrict__ ip,
                         const unsigned int* __restrict__ maskw,
                         const float* __restrict__ timep,
                         const float* __restrict__ dega,
                         const float* __restrict__ degb,
                         const float* __restrict__ xbar,
                         const float* __restrict__ obs,
                         const void* __restrict__ mask,
                         float* __restrict__ wsc,
                         float* __restrict__ xq, float* __restrict__ pq,
                         unsigned char* __restrict__ bm) {
  const int tid = threadIdx.x;
  __shared__ int badsh;
  __shared__ double prod[256];
  __shared__ int sIsI32;
  if (tid == 0) badsh = 0;
  __syncthreads();
  int bad = 0;
  for (int k = tid; k < TF4; k += 256)
    if (maskw[k] > 1u) bad = 1;           // int32 0/1 mask never triggers
  if (bad) atomicOr(&badsh, 1);

  const int i = ip[0];
  double p = 1.0;
  for (int t = tid; t < i; t += 256) p *= alpha_fn(t);
  prod[tid] = p;
  __syncthreads();
  for (int s = 128; s > 0; s >>= 1) {
    if (tid < s) prod[tid] *= prod[tid + s];
    __syncthreads();
  }
  if (tid == 0) {
    sIsI32 = badsh ? 0 : 1;
    if (blockIdx.x == 0) {
      double acp_im1 = prod[0];
      double ai = alpha_fn(i);
      double acp_i = acp_im1 * ai;
      wsc[0] = (float)sqrt(1.0 - acp_i);  // sigma_i
      wsc[1] = (float)acp_i;              // abar_i
      wsc[2] = (float)ai;                 // alpha_i
      wsc[3] = (float)acp_im1;            // abar_{i-1}
      ((int*)wsc)[8] = badsh ? 0 : 1;
    }
  }
  __syncthreads();
  const int isI32 = sIsI32;

  const int pos4 = blockIdx.x * 256 + tid;   // 0..8191
  const int t  = pos4 >> 4;
  const int f0 = (pos4 << 2) & 63;
  const float tv = timep[t];
  f32x4 da = *(const f32x4*)(dega + f0);
  f32x4 db = *(const f32x4*)(degb + f0);
  f32x4 x  = ((const f32x4*)xbar)[pos4];
  f32x4 o  = ((const f32x4*)obs)[pos4];
  i32x4 m  = mload4(mask, isI32, pos4);

  f32x4 xqv, pqv;
  unsigned int bits = 0;
  #pragma unroll
  for (int c = 0; c < 4; ++c) {
    const float pr = fmaf(db[c], tv, da[c]);
    const bool mm = m[c] != 0;
    bits |= mm ? (1u << c) : 0u;
    xqv[c] = mm ? 0.f : x[c];
    pqv[c] = mm ? (o[c] - pr) : pr;
  }
  ((f32x4*)xq)[pos4] = xqv;
  ((f32x4*)pq)[pos4] = pqv;
  bm[pos4] = (unsigned char)bits;
}

// ---------- K2: per-sample score partials (4 samples x 4 k-quarters) ----------
// R9 structure exactly; only table change: sc[] -> bm byte (sv from bits).
__launch_bounds__(256)
__global__ void k2_scores(const float* __restrict__ eps,
                          const float* __restrict__ xq,
                          const float* __restrict__ pq,
                          const unsigned char* __restrict__ bm,
                          const float* __restrict__ wsc,
                          double* __restrict__ pscore) {
  const int tid = threadIdx.x;
  const int n0 = blockIdx.x * 4;
  const int kq = blockIdx.y;
  const int kbeg = kq * (TF4 / 4);           // 2048 positions per quarter
  const float sig = wsc[0];
  const f32x4* e4 = (const f32x4*)eps;
  const f32x4* xq4 = (const f32x4*)xq;
  const f32x4* pq4 = (const f32x4*)pq;

  double acc[4] = {0.0, 0.0, 0.0, 0.0};
  #pragma unroll 2
  for (int k = kbeg + tid; k < kbeg + TF4 / 4; k += 512) {
    const int k1 = k + 256;
    f32x4 xv0 = xq4[k],  pv0 = pq4[k];
    f32x4 xv1 = xq4[k1], pv1 = pq4[k1];
    const unsigned int b0 = bm[k], b1 = bm[k1];
    f32x4 sv0, sv1;
    #pragma unroll
    for (int c = 0; c < 4; ++c) {
      sv0[c] = (b0 & (1u << c)) ? 0.f : sig;
      sv1[c] = (b1 & (1u << c)) ? 0.f : sig;
    }
    #pragma unroll
    for (int r = 0; r < 4; ++r) {
      const size_t row = (size_t)(n0 + r) * TF4;
      f32x4 e0 = e4[row + k];
      f32x4 e1 = e4[row + k1];
      float s = 0.f;
      #pragma unroll
      for (int c = 0; c < 4; ++c) {
        float v = fmaf(e0[c], sv0[c], xv0[c]);
        v = fminf(fmaxf(v, -1.f), 1.f);
        float d = v - pv0[c];
        s = fmaf(d, d, s);
      }
      #pragma unroll
      for (int c = 0; c < 4; ++c) {
        float v = fmaf(e1[c], sv1[c], xv1[c]);
        v = fminf(fmaxf(v, -1.f), 1.f);
        float d = v - pv1[c];
        s = fmaf(d, d, s);
      }
      acc[r] += (double)s;
    }
  }
  __shared__ double red[4 * 256];
  #pragma unroll
  for (int r = 0; r < 4; ++r) red[r * 256 + tid] = acc[r];
  __syncthreads();
  for (int s = 128; s > 0; s >>= 1) {
    if (tid < s) {
      #pragma unroll
      for (int r = 0; r < 4; ++r) red[r * 256 + tid] += red[r * 256 + tid + s];
    }
    __syncthreads();
  }
  if (tid < 4) pscore[kq * NS + n0 + tid] = red[tid * 256];
}

// ---------- K34: softmax+compaction (redundant/block, LDS) + weighted partial ----------
__launch_bounds__(256)
__global__ void k34_weighted(const double* __restrict__ pscore,
                             const float* __restrict__ eps,
                             const float* __restrict__ xbar,
                             const float* __restrict__ wsc,
                             float* __restrict__ partial) {
  const int tid = threadIdx.x;
  __shared__ double red[256];
  __shared__ int cnt[256];
  __shared__ int   ciL[NS];
  __shared__ float cwL[NS];

  float s[8];
  #pragma unroll
  for (int j = 0; j < 8; ++j) {
    int n = tid + 256 * j;
    double t = pscore[n] + pscore[NS + n] + pscore[2 * NS + n] + pscore[3 * NS + n];
    s[j] = -(float)(t * (1.0 / 32768.0));
  }
  double t = 0.0;
  #pragma unroll
  for (int j = 0; j < 8; ++j) t += (double)s[j];
  red[tid] = t; __syncthreads();
  for (int st = 128; st > 0; st >>= 1) { if (tid < st) red[tid] += red[tid + st]; __syncthreads(); }
  const float mean = (float)(red[0] * (1.0 / 2048.0));
  __syncthreads();
  double v = 0.0;
  #pragma unroll
  for (int j = 0; j < 8; ++j) { float d = s[j] - mean; v += (double)d * (double)d; }
  red[tid] = v; __syncthreads();
  for (int st = 128; st > 0; st >>= 1) { if (tid < st) red[tid] += red[tid + st]; __syncthreads(); }
  float stdv = (float)sqrt(red[0] / 2047.0);   // ddof=1
  stdv = fmaxf(stdv, 1e-4f);
  const float inv = 10.0f / stdv;              // /std /0.1
  float lp[8];
  double mx = -1e300;
  #pragma unroll
  for (int j = 0; j < 8; ++j) { lp[j] = (s[j] - mean) * inv; mx = fmax(mx, (double)lp[j]); }
  __syncthreads();
  red[tid] = mx; __syncthreads();
  for (int st = 128; st > 0; st >>= 1) { if (tid < st) red[tid] = fmax(red[tid], red[tid + st]); __syncthreads(); }
  const float M = (float)red[0];
  __syncthreads();
  float ev[8]; double es = 0.0;
  #pragma unroll
  for (int j = 0; j < 8; ++j) { ev[j] = expf(lp[j] - M); es += (double)ev[j]; }
  red[tid] = es; __syncthreads();
  for (int st = 128; st > 0; st >>= 1) { if (tid < st) red[tid] += red[tid + st]; __syncthreads(); }
  const float invS = (float)(1.0 / red[0]);

  float w[8]; int keep[8]; int c = 0;
  #pragma unroll
  for (int j = 0; j < 8; ++j) {
    w[j] = ev[j] * invS;
    keep[j] = w[j] > WCUT;
    c += keep[j];
  }
  cnt[tid] = c; __syncthreads();
  for (int off = 1; off < 256; off <<= 1) {
    int vv = (tid >= off) ? cnt[tid - off] : 0;
    __syncthreads();
    cnt[tid] += vv;
    __syncthreads();
  }
  int base = cnt[tid] - c;              // exclusive prefix
  #pragma unroll
  for (int j = 0; j < 8; ++j) {
    if (keep[j]) {
      ciL[base] = tid + 256 * j;
      cwL[base] = w[j];
      ++base;
    }
  }
  const int Nk = cnt[255];
  __syncthreads();

  const int pos4 = blockIdx.x * 256 + tid;   // 0..8191
  const int g = blockIdx.y;                  // 0..NG-1
  const float sig = wsc[0];
  const f32x4* e4 = (const f32x4*)eps;
  f32x4 xf = ((const f32x4*)xbar)[pos4];
  f32x4 acc = {0.f, 0.f, 0.f, 0.f};
  int j = g;
  for (; j + NG < Nk; j += 2 * NG) {
    const float w0 = cwL[j];
    const int   n0 = ciL[j];
    const float w1 = cwL[j + NG];
    const int   n1 = ciL[j + NG];
    f32x4 e0 = e4[(size_t)n0 * TF4 + pos4];
    f32x4 e1 = e4[(size_t)n1 * TF4 + pos4];
    #pragma unroll
    for (int c2 = 0; c2 < 4; ++c2) {
      float vv = fmaf(e0[c2], sig, xf[c2]);
      vv = fminf(fmaxf(vv, -1.f), 1.f);
      acc[c2] = fmaf(w0, vv, acc[c2]);
    }
    #pragma unroll
    for (int c2 = 0; c2 < 4; ++c2) {
      float vv = fmaf(e1[c2], sig, xf[c2]);
      vv = fminf(fmaxf(vv, -1.f), 1.f);
      acc[c2] = fmaf(w1, vv, acc[c2]);
    }
  }
  for (; j < Nk; j += NG) {
    const float ww = cwL[j];
    const int n = ciL[j];
    f32x4 e = e4[(size_t)n * TF4 + pos4];
    #pragma unroll
    for (int c2 = 0; c2 < 4; ++c2) {
      float vv = fmaf(e[c2], sig, xf[c2]);
      vv = fminf(fmaxf(vv, -1.f), 1.f);
      acc[c2] = fmaf(ww, vv, acc[c2]);
    }
  }
  ((f32x4*)partial)[(size_t)g * TF4 + pos4] = acc;
}

// ---------- K5: reduce partials + final combine -> f32 out ----------
__launch_bounds__(256)
__global__ void k5_final(const float* __restrict__ partial,
                         const float* __restrict__ xbar,
                         const float* __restrict__ obs,
                         const void* __restrict__ mask,
                         const float* __restrict__ wsc,
                         float* __restrict__ out) {
  const int pos4 = blockIdx.x * 256 + threadIdx.x;  // grid 32
  const f32x4* p4 = (const f32x4*)partial;
  f32x4 w = {0.f, 0.f, 0.f, 0.f};
  #pragma unroll 8
  for (int g = 0; g < NG; ++g) {
    f32x4 a = p4[(size_t)g * TF4 + pos4];
    #pragma unroll
    for (int c = 0; c < 4; ++c) w[c] += a[c];
  }
  const float abar = wsc[1];
  const float sa = sqrtf(abar);
  const float ra = 1.f / sqrtf(wsc[2]);
  const float rb = 1.f / sqrtf(wsc[3]);
  const int isI32 = ((const int*)wsc)[8];
  f32x4 xf = ((const f32x4*)xbar)[pos4];
  f32x4 ov = ((const f32x4*)obs)[pos4];
  i32x4 m = mload4(mask, isI32, pos4);
  f32x4 res;
  #pragma unroll
  for (int c = 0; c < 4; ++c) {
    const float Yi = sa * xf[c];
    const float scv = (-Yi + sa * w[c]) / (1.f - abar);
    const float xim1 = (Yi + (1.f - abar) * scv) * ra;
    res[c] = m[c] ? ov[c] : (xim1 * rb);
  }
  ((f32x4*)out)[pos4] = res;
}

extern "C" void kernel_launch(void* const* d_in, const int* in_sizes, int n_in,
                              void* d_out, int out_size, void* d_ws, size_t ws_size,
                              hipStream_t stream) {
  const float* Xbar  = (const float*)d_in[0];
  const float* obs   = (const float*)d_in[1];
  const float* timep = (const float*)d_in[2];
  const void*  mask  = d_in[3];
  const float* eps   = (const float*)d_in[4];
  const float* dega  = (const float*)d_in[5];
  const float* degb  = (const float*)d_in[6];
  const int*   ip    = (const int*)d_in[7];

  float* ws = (float*)d_ws;
  float*  wsc     = ws;                            // 16 floats (+flags)
  float*  xq      = ws + 16;                       // 32768
  float*  pq      = xq + TF;                       // 32768
  unsigned char* bm = (unsigned char*)(pq + TF);   // 8192 bytes
  double* pscore  = (double*)(pq + TF + TF4 / 4);  // 4*2048 doubles (8B-aligned)
  float*  partial = (float*)(pscore + 4 * NS);     // NG*32768 floats (4 MiB)

  hipLaunchKernelGGL(k1_fused,   dim3(32),       dim3(256), 0, stream,
                     ip, (const unsigned int*)mask, timep, dega, degb,
                     Xbar, obs, mask, wsc, xq, pq, bm);
  hipLaunchKernelGGL(k2_scores,  dim3(NS/4, 4),  dim3(256), 0, stream,
                     eps, xq, pq, bm, wsc, pscore);
  hipLaunchKernelGGL(k34_weighted, dim3(32, NG), dim3(256), 0, stream,
                     pscore, eps, Xbar, wsc, partial);
  hipLaunchKernelGGL(k5_final,     dim3(32),     dim3(256), 0, stream,
                     partial, Xbar, obs, mask, wsc, (float*)d_out);
}